// Round 3
// baseline (133.807 us; speedup 1.0000x reference)
//
#include <hip/hip_runtime.h>
#include <stdint.h>

typedef unsigned long long u64;

#define D_DIM   10000
#define C_CLS   128
#define WPRP    192     // padded u64 words per (row-or-class, p)
#define NWORDS  160     // words actually produced by ballots (156 full + 4 tail)
#define NIT     40      // 256-element chunks per 10000-d vector

__device__ __forceinline__ float wred64(float v) {
#pragma unroll
    for (int m = 1; m <= 32; m <<= 1) v += __shfl_xor(v, m);
    return v;
}
__device__ __forceinline__ int wred64i(int v) {
#pragma unroll
    for (int m = 1; m <= 32; m <<= 1) v += __shfl_xor(v, m);
    return v;
}

// ---------------- Kernel A: PQ-HDC transform, one block per class ----------------
__global__ __launch_bounds__(256) void kA_transform(const float* __restrict__ am,
                                                    u64* __restrict__ amw,
                                                    float4* __restrict__ wtab)
{
    const int c = blockIdx.x;
    const int t = threadIdx.x;
    const int w = t >> 6;
    const int l = t & 63;

    __shared__ float redf[4];
    __shared__ int   sI[4][6];
    __shared__ float sF[4][3];

    const float* hvp = am + (size_t)c * D_DIM;

    // wave w handles chunks it = w + 4k; lane l holds d = it*256 + 4l + j (j=0..3)
    float4 loss[10], hv[10];
#pragma unroll
    for (int k = 0; k < 10; ++k) {
        const int it = w + 4 * k;
        const int d0 = it * 256 + 4 * l;
        float4 x = make_float4(0.f, 0.f, 0.f, 0.f);
        if (d0 + 3 < D_DIM) x = *(const float4*)(hvp + d0);
        loss[k] = x; hv[k] = x;
    }

    int cnt[3]; float hX[3]; u64 sp[3];

#pragma unroll
    for (int p = 0; p < 3; ++p) {
        // dot = sum |loss|
        float sabs = 0.f;
#pragma unroll
        for (int k = 0; k < 10; ++k)
            sabs += fabsf(loss[k].x) + fabsf(loss[k].y) + fabsf(loss[k].z) + fabsf(loss[k].w);
        sabs = wred64(sabs);
        if (l == 0) redf[w] = sabs;
        __syncthreads();
        const float dot = redf[0] + redf[1] + redf[2] + redf[3];
        __syncthreads();
        const float dd = dot / (float)D_DIM;

        u64 bits = 0; int cc = 0; float hx = 0.f;
#pragma unroll
        for (int k = 0; k < 10; ++k) {
            const int it = w + 4 * k;
            const bool p0 = loss[k].x > 0.f;
            const bool p1 = loss[k].y > 0.f;
            const bool p2 = loss[k].z > 0.f;
            const bool p3 = loss[k].w > 0.f;
            const u64 b0 = __ballot(p0);
            const u64 b1 = __ballot(p1);
            const u64 b2 = __ballot(p2);
            const u64 b3 = __ballot(p3);
            if (l < 4) {
                const u64 bb = (l == 0) ? b0 : ((l == 1) ? b1 : ((l == 2) ? b2 : b3));
                amw[((size_t)(c * 3 + p)) * WPRP + it * 4 + l] = bb;
            }
            bits |= ((u64)p0 << (4 * k)) | ((u64)p1 << (4 * k + 1))
                  | ((u64)p2 << (4 * k + 2)) | ((u64)p3 << (4 * k + 3));
            cc += (int)p0 + (int)p1 + (int)p2 + (int)p3;
            hx += (p0 ? hv[k].x : -hv[k].x) + (p1 ? hv[k].y : -hv[k].y)
                + (p2 ? hv[k].z : -hv[k].z) + (p3 ? hv[k].w : -hv[k].w);
            float4 L = loss[k];
            L.x -= p0 ? dd : -dd; L.y -= p1 ? dd : -dd;
            L.z -= p2 ? dd : -dd; L.w -= p3 ? dd : -dd;
            const int d0 = it * 256 + 4 * l;
            if (!(d0 + 3 < D_DIM)) L = make_float4(0.f, 0.f, 0.f, 0.f);
            loss[k] = L;
        }
        if (t < WPRP - NWORDS) amw[((size_t)(c * 3 + p)) * WPRP + NWORDS + t] = 0ull;
        sp[p] = bits; cnt[p] = cc; hX[p] = hx;
    }

    // G off-diagonals via per-thread xor popcounts
    int vi[6] = { cnt[0], cnt[1], cnt[2],
                  static_cast<int>(__popcll(sp[0] ^ sp[1])),
                  static_cast<int>(__popcll(sp[0] ^ sp[2])),
                  static_cast<int>(__popcll(sp[1] ^ sp[2])) };
#pragma unroll
    for (int i = 0; i < 6; ++i) vi[i] = wred64i(vi[i]);
    float vf[3] = { hX[0], hX[1], hX[2] };
#pragma unroll
    for (int i = 0; i < 3; ++i) vf[i] = wred64(vf[i]);
    if (l == 0) {
#pragma unroll
        for (int i = 0; i < 6; ++i) sI[w][i] = vi[i];
#pragma unroll
        for (int i = 0; i < 3; ++i) sF[w][i] = vf[i];
    }
    __syncthreads();
    if (t == 0) {
        int a0 = 0, a1 = 0, a2 = 0, X01 = 0, X02 = 0, X12 = 0;
        float h0f = 0, h1f = 0, h2f = 0;
        for (int i = 0; i < 4; ++i) {
            a0 += sI[i][0]; a1 += sI[i][1]; a2 += sI[i][2];
            X01 += sI[i][3]; X02 += sI[i][4]; X12 += sI[i][5];
            h0f += sF[i][0]; h1f += sF[i][1]; h2f += sF[i][2];
        }
        const double Dv = (double)D_DIM;
        const double h0 = h0f, h1 = h1f, h2 = h2f;
        const double g01 = Dv - 2.0 * X01, g02 = Dv - 2.0 * X02, g12 = Dv - 2.0 * X12;
        // adjugate of symmetric G = [[D,g01,g02],[g01,D,g12],[g02,g12,D]]
        const double A00 = Dv * Dv - g12 * g12;
        const double A01 = g02 * g12 - g01 * Dv;
        const double A02 = g01 * g12 - g02 * Dv;
        const double A11 = Dv * Dv - g02 * g02;
        const double A12 = g02 * g01 - Dv * g12;
        const double A22 = Dv * Dv - g01 * g01;
        const double det = Dv * A00 + g01 * A01 + g02 * A02;
        const double w0 = (A00 * h0 + A01 * h1 + A02 * h2) / det;
        const double w1 = (A01 * h0 + A11 * h1 + A12 * h2) / det;
        const double w2 = (A02 * h0 + A12 * h1 + A22 * h2) / det;
        const double s = w0 * w0 + w1 * w1 + w2 * w2;
        const double f0 = w0 * w0 / s, f1 = w1 * w1 / s, f2 = w2 * w2 / s;
        const double cb = -(f0 * a0 + f1 * a1 + f2 * a2);
        wtab[c] = make_float4((float)f0, (float)f1, (float)f2, (float)cb);
    }
}

// ---------------- Kernel B: fused query pack + pseudo-Hamming similarity ----------------
// 8 rows per block; wave w packs rows 2w,2w+1 (exactly the rows its lanes consume).
__global__ __launch_bounds__(256) void kB_phs(const float* __restrict__ query,
                                              const u64* __restrict__ amw,
                                              const float4* __restrict__ wtab,
                                              float* __restrict__ out)
{
    __shared__ u64 qlds[8 * WPRP];     // 12288 B
    __shared__ float4 wsh[C_CLS];      // 2048 B
    const int t = threadIdx.x;
    const int w = t >> 6;
    const int l = t & 63;
    const int r0 = blockIdx.x * 8;

    if (t < C_CLS) wsh[t] = wtab[t];

#pragma unroll
    for (int rr = 0; rr < 2; ++rr) {
        const int rloc = 2 * w + rr;
        const float* qp = query + (size_t)(r0 + rloc) * D_DIM;
        u64* qrow = qlds + rloc * WPRP;
        for (int it = 0; it < NIT; ++it) {
            const int d0 = it * 256 + 4 * l;
            float4 x = make_float4(0.f, 0.f, 0.f, 0.f);
            if (d0 + 3 < D_DIM) x = *(const float4*)(qp + d0);
            const u64 b0 = __ballot(x.x > 0.f);
            const u64 b1 = __ballot(x.y > 0.f);
            const u64 b2 = __ballot(x.z > 0.f);
            const u64 b3 = __ballot(x.w > 0.f);
            if (l < 4) qrow[it * 4 + l] = (l == 0) ? b0 : ((l == 1) ? b1 : ((l == 2) ? b2 : b3));
        }
        if (l < WPRP - NWORDS) qrow[NWORDS + l] = 0ull;
    }
    __syncthreads();

    // phase 2: lane = (row within pair, word-lane); each lane owns 6 contiguous u64
    const int wl = l & 31;
    const int rloc = 2 * w + (l >> 5);
    const int row = r0 + rloc;
    const u64* qr = qlds + rloc * WPRP + wl * 6;
    const u64 q0 = qr[0], q1 = qr[1], q2 = qr[2], q3 = qr[3], q4 = qr[4], q5 = qr[5];

    float qs = (float)(__popcll(q0) + __popcll(q1) + __popcll(q2) +
                       __popcll(q3) + __popcll(q4) + __popcll(q5));
#pragma unroll
    for (int m = 1; m <= 16; m <<= 1) qs += __shfl_xor(qs, m);

    const float base = (float)D_DIM - qs;
    const u64* apbase = amw + (size_t)wl * 6;
    float* orow = out + (size_t)row * C_CLS;

    for (int c = 0; c < C_CLS; ++c) {
        const u64* a0p = apbase + (size_t)c * 3 * WPRP;
        ulonglong2 A0 = *(const ulonglong2*)(a0p);
        ulonglong2 A1 = *(const ulonglong2*)(a0p + 2);
        ulonglong2 A2 = *(const ulonglong2*)(a0p + 4);
        const int pc0 = (int)(__popcll(q0 & A0.x) + __popcll(q1 & A0.y) + __popcll(q2 & A1.x)
                      + __popcll(q3 & A1.y) + __popcll(q4 & A2.x) + __popcll(q5 & A2.y));
        const u64* a1p = a0p + WPRP;
        A0 = *(const ulonglong2*)(a1p);
        A1 = *(const ulonglong2*)(a1p + 2);
        A2 = *(const ulonglong2*)(a1p + 4);
        const int pc1 = (int)(__popcll(q0 & A0.x) + __popcll(q1 & A0.y) + __popcll(q2 & A1.x)
                      + __popcll(q3 & A1.y) + __popcll(q4 & A2.x) + __popcll(q5 & A2.y));
        const u64* a2p = a0p + 2 * WPRP;
        A0 = *(const ulonglong2*)(a2p);
        A1 = *(const ulonglong2*)(a2p + 2);
        A2 = *(const ulonglong2*)(a2p + 4);
        const int pc2 = (int)(__popcll(q0 & A0.x) + __popcll(q1 & A0.y) + __popcll(q2 & A1.x)
                      + __popcll(q3 & A1.y) + __popcll(q4 & A2.x) + __popcll(q5 & A2.y));

        const float4 wv = wsh[c];
        float part = wv.x * (float)pc0 + wv.y * (float)pc1 + wv.z * (float)pc2;
#pragma unroll
        for (int m = 1; m <= 16; m <<= 1) part += __shfl_xor(part, m);
        if (wl == 0) orow[c] = base + wv.w + 2.f * part;
    }
}

extern "C" void kernel_launch(void* const* d_in, const int* in_sizes, int n_in,
                              void* d_out, int out_size, void* d_ws, size_t ws_size,
                              hipStream_t stream)
{
    const float* query = (const float*)d_in[0];
    const float* am    = (const float*)d_in[1];
    float* out = (float*)d_out;

    float4* wtab = (float4*)d_ws;                       // 128 * 16 B
    u64* amw = (u64*)((char*)d_ws + 2048);              // 128*3*192 u64 = 576 KiB

    const int B = in_sizes[0] / D_DIM;                  // 4096

    hipLaunchKernelGGL(kA_transform, dim3(C_CLS), dim3(256), 0, stream, am, amw, wtab);
    hipLaunchKernelGGL(kB_phs, dim3(B / 8), dim3(256), 0, stream, query, amw, wtab, out);
}

// Round 6
// 99.670 us; speedup vs baseline: 1.3425x; 1.3425x over previous
//
#include <hip/hip_runtime.h>
#include <stdint.h>

typedef unsigned long long u64;

#define D_DIM   10000
#define C_CLS   128
#define WPRP    192     // padded u64 words per (row-or-class, p)
#define NWORDS  160     // words actually produced by ballots (156 full + 4 tail)
#define NIT     40      // 256-element chunks per 10000-d vector

__device__ __forceinline__ float wred64(float v) {
#pragma unroll
    for (int m = 1; m <= 32; m <<= 1) v += __shfl_xor(v, m);
    return v;
}
__device__ __forceinline__ int wred64i(int v) {
#pragma unroll
    for (int m = 1; m <= 32; m <<= 1) v += __shfl_xor(v, m);
    return v;
}

// Packed AM layout: amw[((c*32 + word/6)*3 + p)*6 + word%6]
// -> each (class, word-lane) owns 18 contiguous u64 (144 B): p0 words 0-5, p1 6-11, p2 12-17.
__device__ __forceinline__ size_t am_idx(int c, int wi, int p) {
    return ((size_t)c * 32 + (unsigned)wi / 6u) * 18 + (size_t)p * 6 + (unsigned)wi % 6u;
}

// ---------------- Kernel A: PQ-HDC transform, one block per class ----------------
__global__ __launch_bounds__(256) void kA_transform(const float* __restrict__ am,
                                                    u64* __restrict__ amw,
                                                    float4* __restrict__ wtab)
{
    const int c = blockIdx.x;
    const int t = threadIdx.x;
    const int w = t >> 6;
    const int l = t & 63;

    __shared__ float redf[4];
    __shared__ int   sI[4][6];
    __shared__ float sF[4][3];

    const float* hvp = am + (size_t)c * D_DIM;

    // wave w handles chunks it = w + 4k; lane l holds d = it*256 + 4l + j (j=0..3)
    float4 loss[10], hv[10];
#pragma unroll
    for (int k = 0; k < 10; ++k) {
        const int it = w + 4 * k;
        const int d0 = it * 256 + 4 * l;
        float4 x = make_float4(0.f, 0.f, 0.f, 0.f);
        if (d0 + 3 < D_DIM) x = *(const float4*)(hvp + d0);
        loss[k] = x; hv[k] = x;
    }

    int cnt[3]; float hX[3]; u64 sp[3];

#pragma unroll
    for (int p = 0; p < 3; ++p) {
        // dot = sum |loss|
        float sabs = 0.f;
#pragma unroll
        for (int k = 0; k < 10; ++k)
            sabs += fabsf(loss[k].x) + fabsf(loss[k].y) + fabsf(loss[k].z) + fabsf(loss[k].w);
        sabs = wred64(sabs);
        if (l == 0) redf[w] = sabs;
        __syncthreads();
        const float dot = redf[0] + redf[1] + redf[2] + redf[3];
        __syncthreads();
        const float dd = dot / (float)D_DIM;

        u64 bits = 0; int cc = 0; float hx = 0.f;
#pragma unroll
        for (int k = 0; k < 10; ++k) {
            const int it = w + 4 * k;
            const bool p0 = loss[k].x > 0.f;
            const bool p1 = loss[k].y > 0.f;
            const bool p2 = loss[k].z > 0.f;
            const bool p3 = loss[k].w > 0.f;
            const u64 b0 = __ballot(p0);
            const u64 b1 = __ballot(p1);
            const u64 b2 = __ballot(p2);
            const u64 b3 = __ballot(p3);
            if (l < 4) {
                const u64 bb = (l == 0) ? b0 : ((l == 1) ? b1 : ((l == 2) ? b2 : b3));
                amw[am_idx(c, it * 4 + l, p)] = bb;
            }
            bits |= ((u64)p0 << (4 * k)) | ((u64)p1 << (4 * k + 1))
                  | ((u64)p2 << (4 * k + 2)) | ((u64)p3 << (4 * k + 3));
            cc += (int)p0 + (int)p1 + (int)p2 + (int)p3;
            hx += (p0 ? hv[k].x : -hv[k].x) + (p1 ? hv[k].y : -hv[k].y)
                + (p2 ? hv[k].z : -hv[k].z) + (p3 ? hv[k].w : -hv[k].w);
            float4 L = loss[k];
            L.x -= p0 ? dd : -dd; L.y -= p1 ? dd : -dd;
            L.z -= p2 ? dd : -dd; L.w -= p3 ? dd : -dd;
            const int d0 = it * 256 + 4 * l;
            if (!(d0 + 3 < D_DIM)) L = make_float4(0.f, 0.f, 0.f, 0.f);
            loss[k] = L;
        }
        if (t < WPRP - NWORDS) amw[am_idx(c, NWORDS + t, p)] = 0ull;
        sp[p] = bits; cnt[p] = cc; hX[p] = hx;
    }

    // G off-diagonals via per-thread xor popcounts
    int vi[6] = { cnt[0], cnt[1], cnt[2],
                  static_cast<int>(__popcll(sp[0] ^ sp[1])),
                  static_cast<int>(__popcll(sp[0] ^ sp[2])),
                  static_cast<int>(__popcll(sp[1] ^ sp[2])) };
#pragma unroll
    for (int i = 0; i < 6; ++i) vi[i] = wred64i(vi[i]);
    float vf[3] = { hX[0], hX[1], hX[2] };
#pragma unroll
    for (int i = 0; i < 3; ++i) vf[i] = wred64(vf[i]);
    if (l == 0) {
#pragma unroll
        for (int i = 0; i < 6; ++i) sI[w][i] = vi[i];
#pragma unroll
        for (int i = 0; i < 3; ++i) sF[w][i] = vf[i];
    }
    __syncthreads();
    if (t == 0) {
        int a0 = 0, a1 = 0, a2 = 0, X01 = 0, X02 = 0, X12 = 0;
        float h0f = 0, h1f = 0, h2f = 0;
        for (int i = 0; i < 4; ++i) {
            a0 += sI[i][0]; a1 += sI[i][1]; a2 += sI[i][2];
            X01 += sI[i][3]; X02 += sI[i][4]; X12 += sI[i][5];
            h0f += sF[i][0]; h1f += sF[i][1]; h2f += sF[i][2];
        }
        const double Dv = (double)D_DIM;
        const double h0 = h0f, h1 = h1f, h2 = h2f;
        const double g01 = Dv - 2.0 * X01, g02 = Dv - 2.0 * X02, g12 = Dv - 2.0 * X12;
        // adjugate of symmetric G = [[D,g01,g02],[g01,D,g12],[g02,g12,D]]
        const double A00 = Dv * Dv - g12 * g12;
        const double A01 = g02 * g12 - g01 * Dv;
        const double A02 = g01 * g12 - g02 * Dv;
        const double A11 = Dv * Dv - g02 * g02;
        const double A12 = g02 * g01 - Dv * g12;
        const double A22 = Dv * Dv - g01 * g01;
        const double det = Dv * A00 + g01 * A01 + g02 * A02;
        const double w0 = (A00 * h0 + A01 * h1 + A02 * h2) / det;
        const double w1 = (A01 * h0 + A11 * h1 + A12 * h2) / det;
        const double w2 = (A02 * h0 + A12 * h1 + A22 * h2) / det;
        const double s = w0 * w0 + w1 * w1 + w2 * w2;
        const double f0 = w0 * w0 / s, f1 = w1 * w1 / s, f2 = w2 * w2 / s;
        const double cb = -(f0 * a0 + f1 * a1 + f2 * a2);
        wtab[c] = make_float4((float)f0, (float)f1, (float)f2, (float)cb);
    }
}

// ---------------- Kernel B: fused query pack + pseudo-Hamming similarity ----------------
// 4 rows per block (grid = B/4 = 1024). Wave w packs row w, then handles classes
// [32w, 32w+32). Lane = (row-half rh, word-lane wl): q words held in registers for
// the whole class loop; both halves read identical AM addresses (1x L2 traffic).
__global__ __launch_bounds__(256, 4) void kB_phs(const float* __restrict__ query,
                                                 const u64* __restrict__ amw,
                                                 const float4* __restrict__ wtab,
                                                 float* __restrict__ out)
{
    __shared__ u64 qlds[4 * WPRP];     // 6144 B
    __shared__ float4 wsh[C_CLS];      // 2048 B
    const int t = threadIdx.x;
    const int w = t >> 6;
    const int l = t & 63;
    const int r0 = blockIdx.x * 4;

    if (t < C_CLS) wsh[t] = wtab[t];

    // ---- pack: wave w packs row r0 + w ----
    {
        const float* qp = query + (size_t)(r0 + w) * D_DIM;
        u64* qrow = qlds + w * WPRP;
        for (int it = 0; it < NIT; ++it) {
            const int d0 = it * 256 + 4 * l;
            float4 x = make_float4(0.f, 0.f, 0.f, 0.f);
            if (d0 + 3 < D_DIM) x = *(const float4*)(qp + d0);
            const u64 b0 = __ballot(x.x > 0.f);
            const u64 b1 = __ballot(x.y > 0.f);
            const u64 b2 = __ballot(x.z > 0.f);
            const u64 b3 = __ballot(x.w > 0.f);
            if (l < 4) qrow[it * 4 + l] = (l == 0) ? b0 : ((l == 1) ? b1 : ((l == 2) ? b2 : b3));
        }
        if (l < 32) qrow[NWORDS + l] = 0ull;
    }
    __syncthreads();

    // ---- PHS: lane owns rows {2rh, 2rh+1}, word slot wl (6 u64 each) ----
    const int wl = l & 31;
    const int rh = l >> 5;
    const int rA = 2 * rh, rB = 2 * rh + 1;

    const u64* qa = qlds + rA * WPRP + wl * 6;
    const u64* qb = qlds + rB * WPRP + wl * 6;
    const u64 qa0 = qa[0], qa1 = qa[1], qa2 = qa[2], qa3 = qa[3], qa4 = qa[4], qa5 = qa[5];
    const u64 qb0 = qb[0], qb1 = qb[1], qb2 = qb[2], qb3 = qb[3], qb4 = qb[4], qb5 = qb[5];

    float sA = (float)(__popcll(qa0) + __popcll(qa1) + __popcll(qa2) +
                       __popcll(qa3) + __popcll(qa4) + __popcll(qa5));
    float sB = (float)(__popcll(qb0) + __popcll(qb1) + __popcll(qb2) +
                       __popcll(qb3) + __popcll(qb4) + __popcll(qb5));
#pragma unroll
    for (int m = 1; m <= 16; m <<= 1) { sA += __shfl_xor(sA, m); sB += __shfl_xor(sB, m); }
    const float baseA = (float)D_DIM - sA;
    const float baseB = (float)D_DIM - sB;

    float* orowA = out + (size_t)(r0 + rA) * C_CLS;
    float* orowB = out + (size_t)(r0 + rB) * C_CLS;

    const int c0 = 32 * w;
#pragma unroll 2
    for (int i = 0; i < 32; ++i) {
        const int c = c0 + i;
        const u64* ap = amw + ((size_t)c * 32 + wl) * 18;
        const ulonglong2 v0 = *(const ulonglong2*)(ap + 0);
        const ulonglong2 v1 = *(const ulonglong2*)(ap + 2);
        const ulonglong2 v2 = *(const ulonglong2*)(ap + 4);
        const ulonglong2 v3 = *(const ulonglong2*)(ap + 6);
        const ulonglong2 v4 = *(const ulonglong2*)(ap + 8);
        const ulonglong2 v5 = *(const ulonglong2*)(ap + 10);
        const ulonglong2 v6 = *(const ulonglong2*)(ap + 12);
        const ulonglong2 v7 = *(const ulonglong2*)(ap + 14);
        const ulonglong2 v8 = *(const ulonglong2*)(ap + 16);

        const int pA0 = (int)(__popcll(qa0 & v0.x) + __popcll(qa1 & v0.y) + __popcll(qa2 & v1.x)
                      + __popcll(qa3 & v1.y) + __popcll(qa4 & v2.x) + __popcll(qa5 & v2.y));
        const int pA1 = (int)(__popcll(qa0 & v3.x) + __popcll(qa1 & v3.y) + __popcll(qa2 & v4.x)
                      + __popcll(qa3 & v4.y) + __popcll(qa4 & v5.x) + __popcll(qa5 & v5.y));
        const int pA2 = (int)(__popcll(qa0 & v6.x) + __popcll(qa1 & v6.y) + __popcll(qa2 & v7.x)
                      + __popcll(qa3 & v7.y) + __popcll(qa4 & v8.x) + __popcll(qa5 & v8.y));
        const int pB0 = (int)(__popcll(qb0 & v0.x) + __popcll(qb1 & v0.y) + __popcll(qb2 & v1.x)
                      + __popcll(qb3 & v1.y) + __popcll(qb4 & v2.x) + __popcll(qb5 & v2.y));
        const int pB1 = (int)(__popcll(qb0 & v3.x) + __popcll(qb1 & v3.y) + __popcll(qb2 & v4.x)
                      + __popcll(qb3 & v4.y) + __popcll(qb4 & v5.x) + __popcll(qb5 & v5.y));
        const int pB2 = (int)(__popcll(qb0 & v6.x) + __popcll(qb1 & v6.y) + __popcll(qb2 & v7.x)
                      + __popcll(qb3 & v7.y) + __popcll(qb4 & v8.x) + __popcll(qb5 & v8.y));

        const float4 wv = wsh[c];
        float partA = wv.x * (float)pA0 + wv.y * (float)pA1 + wv.z * (float)pA2;
        float partB = wv.x * (float)pB0 + wv.y * (float)pB1 + wv.z * (float)pB2;
#pragma unroll
        for (int m = 1; m <= 16; m <<= 1) {
            partA += __shfl_xor(partA, m);
            partB += __shfl_xor(partB, m);
        }
        if (wl == 0) {
            orowA[c] = baseA + wv.w + 2.f * partA;
            orowB[c] = baseB + wv.w + 2.f * partB;
        }
    }
}

extern "C" void kernel_launch(void* const* d_in, const int* in_sizes, int n_in,
                              void* d_out, int out_size, void* d_ws, size_t ws_size,
                              hipStream_t stream)
{
    const float* query = (const float*)d_in[0];
    const float* am    = (const float*)d_in[1];
    float* out = (float*)d_out;

    float4* wtab = (float4*)d_ws;                       // 128 * 16 B
    u64* amw = (u64*)((char*)d_ws + 2048);              // 128*32*18 u64 = 576 KiB

    const int B = in_sizes[0] / D_DIM;                  // 4096

    hipLaunchKernelGGL(kA_transform, dim3(C_CLS), dim3(256), 0, stream, am, amw, wtab);
    hipLaunchKernelGGL(kB_phs, dim3(B / 4), dim3(256), 0, stream, query, amw, wtab, out);
}

// Round 7
// 96.819 us; speedup vs baseline: 1.3820x; 1.0295x over previous
//
#include <hip/hip_runtime.h>
#include <stdint.h>

typedef unsigned long long u64;

#define D_DIM   10000
#define C_CLS   128
#define WPRP    192     // padded u64 words per (row-or-class, p)
#define NWORDS  160     // words actually produced by ballots (156 full + 4 tail)
#define NIT     40      // 256-element chunks per 10000-d vector
#define GRP     8       // classes per reduction group

__device__ __forceinline__ float wred64(float v) {
#pragma unroll
    for (int m = 1; m <= 32; m <<= 1) v += __shfl_xor(v, m);
    return v;
}
__device__ __forceinline__ int wred64i(int v) {
#pragma unroll
    for (int m = 1; m <= 32; m <<= 1) v += __shfl_xor(v, m);
    return v;
}

// Packed AM layout: each (class, word-lane) owns 18 contiguous u64 (144 B):
// p0 words 0-5, p1 6-11, p2 12-17.
__device__ __forceinline__ size_t am_idx(int c, int wi, int p) {
    return ((size_t)c * 32 + (unsigned)wi / 6u) * 18 + (size_t)p * 6 + (unsigned)wi % 6u;
}

// ---------------- Kernel A: PQ-HDC transform, one block per class ----------------
__global__ __launch_bounds__(256) void kA_transform(const float* __restrict__ am,
                                                    u64* __restrict__ amw,
                                                    float4* __restrict__ wtab)
{
    const int c = blockIdx.x;
    const int t = threadIdx.x;
    const int w = t >> 6;
    const int l = t & 63;

    __shared__ float redf[4];
    __shared__ int   sI[4][6];
    __shared__ float sF[4][3];

    const float* hvp = am + (size_t)c * D_DIM;

    float4 loss[10], hv[10];
#pragma unroll
    for (int k = 0; k < 10; ++k) {
        const int it = w + 4 * k;
        const int d0 = it * 256 + 4 * l;
        float4 x = make_float4(0.f, 0.f, 0.f, 0.f);
        if (d0 + 3 < D_DIM) x = *(const float4*)(hvp + d0);
        loss[k] = x; hv[k] = x;
    }

    int cnt[3]; float hX[3]; u64 sp[3];

#pragma unroll
    for (int p = 0; p < 3; ++p) {
        float sabs = 0.f;
#pragma unroll
        for (int k = 0; k < 10; ++k)
            sabs += fabsf(loss[k].x) + fabsf(loss[k].y) + fabsf(loss[k].z) + fabsf(loss[k].w);
        sabs = wred64(sabs);
        if (l == 0) redf[w] = sabs;
        __syncthreads();
        const float dot = redf[0] + redf[1] + redf[2] + redf[3];
        __syncthreads();
        const float dd = dot / (float)D_DIM;

        u64 bits = 0; int cc = 0; float hx = 0.f;
#pragma unroll
        for (int k = 0; k < 10; ++k) {
            const int it = w + 4 * k;
            const bool p0 = loss[k].x > 0.f;
            const bool p1 = loss[k].y > 0.f;
            const bool p2 = loss[k].z > 0.f;
            const bool p3 = loss[k].w > 0.f;
            const u64 b0 = __ballot(p0);
            const u64 b1 = __ballot(p1);
            const u64 b2 = __ballot(p2);
            const u64 b3 = __ballot(p3);
            if (l < 4) {
                const u64 bb = (l == 0) ? b0 : ((l == 1) ? b1 : ((l == 2) ? b2 : b3));
                amw[am_idx(c, it * 4 + l, p)] = bb;
            }
            bits |= ((u64)p0 << (4 * k)) | ((u64)p1 << (4 * k + 1))
                  | ((u64)p2 << (4 * k + 2)) | ((u64)p3 << (4 * k + 3));
            cc += (int)p0 + (int)p1 + (int)p2 + (int)p3;
            hx += (p0 ? hv[k].x : -hv[k].x) + (p1 ? hv[k].y : -hv[k].y)
                + (p2 ? hv[k].z : -hv[k].z) + (p3 ? hv[k].w : -hv[k].w);
            float4 L = loss[k];
            L.x -= p0 ? dd : -dd; L.y -= p1 ? dd : -dd;
            L.z -= p2 ? dd : -dd; L.w -= p3 ? dd : -dd;
            const int d0 = it * 256 + 4 * l;
            if (!(d0 + 3 < D_DIM)) L = make_float4(0.f, 0.f, 0.f, 0.f);
            loss[k] = L;
        }
        if (t < WPRP - NWORDS) amw[am_idx(c, NWORDS + t, p)] = 0ull;
        sp[p] = bits; cnt[p] = cc; hX[p] = hx;
    }

    int vi[6] = { cnt[0], cnt[1], cnt[2],
                  static_cast<int>(__popcll(sp[0] ^ sp[1])),
                  static_cast<int>(__popcll(sp[0] ^ sp[2])),
                  static_cast<int>(__popcll(sp[1] ^ sp[2])) };
#pragma unroll
    for (int i = 0; i < 6; ++i) vi[i] = wred64i(vi[i]);
    float vf[3] = { hX[0], hX[1], hX[2] };
#pragma unroll
    for (int i = 0; i < 3; ++i) vf[i] = wred64(vf[i]);
    if (l == 0) {
#pragma unroll
        for (int i = 0; i < 6; ++i) sI[w][i] = vi[i];
#pragma unroll
        for (int i = 0; i < 3; ++i) sF[w][i] = vf[i];
    }
    __syncthreads();
    if (t == 0) {
        int a0 = 0, a1 = 0, a2 = 0, X01 = 0, X02 = 0, X12 = 0;
        float h0f = 0, h1f = 0, h2f = 0;
        for (int i = 0; i < 4; ++i) {
            a0 += sI[i][0]; a1 += sI[i][1]; a2 += sI[i][2];
            X01 += sI[i][3]; X02 += sI[i][4]; X12 += sI[i][5];
            h0f += sF[i][0]; h1f += sF[i][1]; h2f += sF[i][2];
        }
        const double Dv = (double)D_DIM;
        const double h0 = h0f, h1 = h1f, h2 = h2f;
        const double g01 = Dv - 2.0 * X01, g02 = Dv - 2.0 * X02, g12 = Dv - 2.0 * X12;
        const double A00 = Dv * Dv - g12 * g12;
        const double A01 = g02 * g12 - g01 * Dv;
        const double A02 = g01 * g12 - g02 * Dv;
        const double A11 = Dv * Dv - g02 * g02;
        const double A12 = g02 * g01 - Dv * g12;
        const double A22 = Dv * Dv - g01 * g01;
        const double det = Dv * A00 + g01 * A01 + g02 * A02;
        const double w0 = (A00 * h0 + A01 * h1 + A02 * h2) / det;
        const double w1 = (A01 * h0 + A11 * h1 + A12 * h2) / det;
        const double w2 = (A02 * h0 + A12 * h1 + A22 * h2) / det;
        const double s = w0 * w0 + w1 * w1 + w2 * w2;
        const double f0 = w0 * w0 / s, f1 = w1 * w1 / s, f2 = w2 * w2 / s;
        const double cb = -(f0 * a0 + f1 * a1 + f2 * a2);
        wtab[c] = make_float4((float)f0, (float)f1, (float)f2, (float)cb);
    }
}

// ---------------- Kernel B: fused query pack + pseudo-Hamming similarity ----------------
// 4 rows/block, grid = B/4. Wave w packs row w, then handles classes [32w,32w+32)
// for all 4 rows (lane halves rh=0/1 own row pairs {0,1}/{2,3}; both halves read
// identical AM addresses -> 1x L2 traffic). Per-class lane partials fold in the
// base terms (312.5 - qs_lane + w.w/32), so out[row][c] = sum over 32 lanes.
// Reduction: 8-class groups via padded-LDS transpose (no dependent shuffle chains),
// then coalesced stores with lane<->(row,class) mapping.
__global__ __launch_bounds__(256, 4) void kB_phs(const float* __restrict__ query,
                                                 const u64* __restrict__ amw,
                                                 const float4* __restrict__ wtab,
                                                 float* __restrict__ out)
{
    __shared__ u64 qlds[4 * WPRP];          // 6144 B
    __shared__ float4 wsh[C_CLS];           // 2048 B
    __shared__ float part[4][4][GRP][33];   // [wave][row_loc][cc][wl] 16896 B
    const int t = threadIdx.x;
    const int w = t >> 6;
    const int l = t & 63;
    const int r0 = blockIdx.x * 4;

    if (t < C_CLS) wsh[t] = wtab[t];

    // ---- pack: wave w packs row r0 + w ----
    {
        const float* qp = query + (size_t)(r0 + w) * D_DIM;
        u64* qrow = qlds + w * WPRP;
        for (int it = 0; it < NIT; ++it) {
            const int d0 = it * 256 + 4 * l;
            float4 x = make_float4(0.f, 0.f, 0.f, 0.f);
            if (d0 + 3 < D_DIM) x = *(const float4*)(qp + d0);
            const u64 b0 = __ballot(x.x > 0.f);
            const u64 b1 = __ballot(x.y > 0.f);
            const u64 b2 = __ballot(x.z > 0.f);
            const u64 b3 = __ballot(x.w > 0.f);
            if (l < 4) qrow[it * 4 + l] = (l == 0) ? b0 : ((l == 1) ? b1 : ((l == 2) ? b2 : b3));
        }
        if (l < 32) qrow[NWORDS + l] = 0ull;
    }
    __syncthreads();

    // ---- per-lane q words: rows 2rh, 2rh+1, word slot wl (6 u64 each) ----
    const int wl = l & 31;
    const int rh = l >> 5;
    const int rA = 2 * rh, rB = 2 * rh + 1;

    const u64* qa = qlds + rA * WPRP + wl * 6;
    const u64* qb = qlds + rB * WPRP + wl * 6;
    const u64 qa0 = qa[0], qa1 = qa[1], qa2 = qa[2], qa3 = qa[3], qa4 = qa[4], qa5 = qa[5];
    const u64 qb0 = qb[0], qb1 = qb[1], qb2 = qb[2], qb3 = qb[3], qb4 = qb[4], qb5 = qb[5];

    const int qsA = (int)(__popcll(qa0) + __popcll(qa1) + __popcll(qa2) +
                          __popcll(qa3) + __popcll(qa4) + __popcll(qa5));
    const int qsB = (int)(__popcll(qb0) + __popcll(qb1) + __popcll(qb2) +
                          __popcll(qb3) + __popcll(qb4) + __popcll(qb5));
    const float offA = 312.5f - (float)qsA;   // D/32 - qs_lane  (both exact in f32)
    const float offB = 312.5f - (float)qsB;

    // reader mapping for the transpose-reduce
    const int o = l >> 1;            // 0..31
    const int row_loc = o >> 3;      // 0..3
    const int cc = o & 7;            // 0..7
    const int h = l & 1;             // half of the lane dimension

    const int c0 = 32 * w;
    float (*pw)[GRP][33] = part[w];

    for (int g = 0; g < 4; ++g) {
        float accA[GRP], accB[GRP];
#pragma unroll
        for (int i = 0; i < GRP; ++i) {
            const int c = c0 + g * GRP + i;
            const u64* ap = amw + ((size_t)c * 32 + wl) * 18;
            const ulonglong2 v0 = *(const ulonglong2*)(ap + 0);
            const ulonglong2 v1 = *(const ulonglong2*)(ap + 2);
            const ulonglong2 v2 = *(const ulonglong2*)(ap + 4);
            const ulonglong2 v3 = *(const ulonglong2*)(ap + 6);
            const ulonglong2 v4 = *(const ulonglong2*)(ap + 8);
            const ulonglong2 v5 = *(const ulonglong2*)(ap + 10);
            const ulonglong2 v6 = *(const ulonglong2*)(ap + 12);
            const ulonglong2 v7 = *(const ulonglong2*)(ap + 14);
            const ulonglong2 v8 = *(const ulonglong2*)(ap + 16);

            const int pA0 = (int)(__popcll(qa0 & v0.x) + __popcll(qa1 & v0.y) + __popcll(qa2 & v1.x)
                          + __popcll(qa3 & v1.y) + __popcll(qa4 & v2.x) + __popcll(qa5 & v2.y));
            const int pA1 = (int)(__popcll(qa0 & v3.x) + __popcll(qa1 & v3.y) + __popcll(qa2 & v4.x)
                          + __popcll(qa3 & v4.y) + __popcll(qa4 & v5.x) + __popcll(qa5 & v5.y));
            const int pA2 = (int)(__popcll(qa0 & v6.x) + __popcll(qa1 & v6.y) + __popcll(qa2 & v7.x)
                          + __popcll(qa3 & v7.y) + __popcll(qa4 & v8.x) + __popcll(qa5 & v8.y));
            const int pB0 = (int)(__popcll(qb0 & v0.x) + __popcll(qb1 & v0.y) + __popcll(qb2 & v1.x)
                          + __popcll(qb3 & v1.y) + __popcll(qb4 & v2.x) + __popcll(qb5 & v2.y));
            const int pB1 = (int)(__popcll(qb0 & v3.x) + __popcll(qb1 & v3.y) + __popcll(qb2 & v4.x)
                          + __popcll(qb3 & v4.y) + __popcll(qb4 & v5.x) + __popcll(qb5 & v5.y));
            const int pB2 = (int)(__popcll(qb0 & v6.x) + __popcll(qb1 & v6.y) + __popcll(qb2 & v7.x)
                          + __popcll(qb3 & v7.y) + __popcll(qb4 & v8.x) + __popcll(qb5 & v8.y));

            const float4 wv = wsh[c];
            const float cw = wv.w * 0.03125f;   // w.w / 32, exact
            accA[i] = fmaf(2.f, wv.x * (float)pA0 + wv.y * (float)pA1 + wv.z * (float)pA2,
                           offA + cw);
            accB[i] = fmaf(2.f, wv.x * (float)pB0 + wv.y * (float)pB1 + wv.z * (float)pB2,
                           offB + cw);
        }

        // ---- transpose-reduce through LDS (per-wave buffer, 2 lanes/bank = free) ----
#pragma unroll
        for (int i = 0; i < GRP; ++i) {
            pw[rA][i][wl] = accA[i];
            pw[rB][i][wl] = accB[i];
        }
        __syncthreads();   // intra-wave RAW + keeps waves convergent

        float s = 0.f;
#pragma unroll
        for (int j = 0; j < 16; ++j) s += pw[row_loc][cc][h * 16 + j];
        s += __shfl_xor(s, 1);
        if (h == 0)
            out[(size_t)(r0 + row_loc) * C_CLS + (c0 + g * GRP + cc)] = s;
        __syncthreads();   // WAR before next group's writes
    }
}

extern "C" void kernel_launch(void* const* d_in, const int* in_sizes, int n_in,
                              void* d_out, int out_size, void* d_ws, size_t ws_size,
                              hipStream_t stream)
{
    const float* query = (const float*)d_in[0];
    const float* am    = (const float*)d_in[1];
    float* out = (float*)d_out;

    float4* wtab = (float4*)d_ws;                       // 128 * 16 B
    u64* amw = (u64*)((char*)d_ws + 2048);              // 128*32*18 u64 = 576 KiB

    const int B = in_sizes[0] / D_DIM;                  // 4096

    hipLaunchKernelGGL(kA_transform, dim3(C_CLS), dim3(256), 0, stream, am, amw, wtab);
    hipLaunchKernelGGL(kB_phs, dim3(B / 4), dim3(256), 0, stream, query, amw, wtab, out);
}